// Round 6
// baseline (100.573 us; speedup 1.0000x reference)
//
#include <hip/hip_runtime.h>
#include <stdint.h>

// Y = tanh(X @ W + b):  M=65536 (8*64*128), K=512, N=512, all fp32.
// R6: single-pass. A staged as RAW FP32 via global_load_lds (zero staging
// VGPRs, single vmcnt drain per step); fp32->bf16 cvt happens on the LDS
// fragment read (8 pk2 per A-frag), overlapped with MFMA. Read-side XOR
// swizzle realized by pre-swizzling the per-lane GLOBAL source address
// (linear LDS dest, m173 pattern). W pre-converted once (cvtW) to a bf16
// transposed swizzled tile image so B staging is pure global_load_lds.
// LDS = A 32KB (fp32 [128][64]) + B 16KB = 48KB -> 3 blocks/CU.
// R5 lesson: reg-staged A puts X latency between barriers (+35us).
// R2/R3 lesson: cross-step register prefetch spills under the VGPR cap.

typedef short bf16x8 __attribute__((ext_vector_type(8)));
typedef float f32x16 __attribute__((ext_vector_type(16)));
typedef uint32_t u32x4 __attribute__((ext_vector_type(4)));

#define KTOT 512
#define NTOT 512
#define BK   64
#define WT_BYTES   524288ull      // 512*512*2
#define WS_NEEDED  WT_BYTES

typedef __attribute__((address_space(3))) uint8_t lds8;
typedef __attribute__((address_space(1))) const uint8_t glb8;

__device__ __forceinline__ uint32_t pk2(float a, float b) {
  uint16_t lo = __builtin_bit_cast(uint16_t, (__bf16)a);   // RNE
  uint16_t hi = __builtin_bit_cast(uint16_t, (__bf16)b);
  return (uint32_t)lo | ((uint32_t)hi << 16);
}

__device__ __forceinline__ bf16x8 pack8(float4 a, float4 b) {
  u32x4 t;
  t.x = pk2(a.x, a.y); t.y = pk2(a.z, a.w);
  t.z = pk2(b.x, b.y); t.w = pk2(b.z, b.w);
  return __builtin_bit_cast(bf16x8, t);
}

__device__ __forceinline__ float fast_tanh(float z) {
  float t = __builtin_amdgcn_exp2f(z * 2.8853900817779268f);
  return 1.0f - 2.0f * __builtin_amdgcn_rcpf(t + 1.0f);
}

// ------- pass 1: W fp32 [k][n] -> bf16 transposed swizzled tile image -------
// Image: 32 tiles (tn 0..3, ts 0..7) of 16KB: [n:128 rows][8 chunks of 16B],
// chunk j stored at slot j^(row&7).
__global__ __launch_bounds__(256)
void cvtW_kernel(const float* __restrict__ W, uint8_t* __restrict__ Wt) {
  const int c   = blockIdx.x * 256 + threadIdx.x;     // 0..32767
  const int j   = c & 7;
  const int r   = (c >> 3) & 127;                     // local n
  const int tsn = c >> 10;                            // tn*8+ts, 0..31
  const int ts  = tsn & 7;
  const int tn  = tsn >> 3;
  const int n   = tn * 128 + r;
  const int k0  = ts * 64 + j * 8;
  float e[8];
#pragma unroll
  for (int i = 0; i < 8; ++i) e[i] = W[(size_t)(k0 + i) * NTOT + n];
  uint4 v = make_uint4(pk2(e[0], e[1]), pk2(e[2], e[3]), pk2(e[4], e[5]), pk2(e[6], e[7]));
  *(uint4*)(Wt + ((size_t)tsn << 14) + (r << 7) + ((j ^ (r & 7)) << 4)) = v;
}

// ---------------- pass 2: fused GEMM (A fp32-in-LDS) + bias + tanh ----------
__global__ __launch_bounds__(256, 3)
void hotdd_fused(const float* __restrict__ X, const uint8_t* __restrict__ Wt,
                 const float* __restrict__ Bv, float* __restrict__ Y) {
  __shared__ uint8_t Ab[32768];   // A tile [m:128][k:64] FP32; 16 chunks/row,
                                  // LDS slot c holds global chunk c^(row&7)
  __shared__ uint8_t Bb[16384];   // W^T tile [n:128][k:64] bf16, swizzled

  // XCD swizzle: the 4 bn-blocks sharing an X strip get dispatch ids
  // {d, d+8, d+16, d+24} -> same XCD, consecutive in its queue -> X strip
  // re-reads are L2-local.
  const int d  = blockIdx.x;
  const int bm = ((d >> 5) << 3) | (d & 7);   // 0..511
  const int bn = (d >> 3) & 3;                // 0..3

  const int tid  = threadIdx.x;
  const int lane = tid & 63;
  const int wv   = tid >> 6;
  const int wr   = (wv >> 1) * 64;
  const int wc   = (wv & 1) * 64;
  const int lo5  = lane & 31;
  const int hi1  = lane >> 5;
  const int rs   = lo5 & 7;

  // ---- A staging (global_load_lds, fp32, swizzled source):
  // wave wv owns rows [wv*32, wv*32+32). 8 chunks of 1KB; chunk q = 4 rows.
  // lane l -> row_local l>>4, slot l&15; fetches global chunk (l&15)^key,
  // key = row&7 = (l>>4) + 4*(q&1).
  const int l15 = lane & 15;
  const int l4  = lane >> 4;
  const int ce  = l15 ^ l4;         // global chunk, even q
  const int co  = ce ^ 4;           // global chunk, odd q
  const float* pA = X + (size_t)(bm * 128 + wv * 32 + l4) * KTOT;
  uint8_t* AdstW = Ab + wv * 8192;  // wave-uniform; HW adds lane*16

  // ---- B staging: wave wv copies bytes [wv*4096, +4096) of the 16KB tile.
  const uint8_t* Bsrc = Wt + ((size_t)(bn * 8) << 14) + wv * 4096 + lane * 16;
  uint8_t* Bdst = Bb + wv * 4096;

  f32x16 acc00 = {}, acc01 = {}, acc10 = {}, acc11 = {};

  const uint8_t* ArdA = Ab + (wr + lo5) * 256;   // fp32 row = 256B
  const uint8_t* ArdB = ArdA + 32 * 256;
  const uint8_t* Brd0 = Bb + (wc + lo5) * 128;
  const uint8_t* Brd1 = Brd0 + 32 * 128;

#pragma unroll 1
  for (int s = 0; s < 8; ++s) {
    // 1) issue A async global->LDS (fp32, 8KB/wave)
    {
      const float* base = pA + s * BK;
#pragma unroll
      for (int q = 0; q < 8; ++q) {
        const float* src = base + (size_t)(q * 4) * KTOT + ((q & 1) ? co : ce) * 4;
        __builtin_amdgcn_global_load_lds((glb8*)src, (lds8*)(AdstW + q * 1024),
                                         16, 0, 0);
      }
    }
    // 2) issue B async global->LDS (bf16 image, 4KB/wave)
    {
      const uint8_t* bs_ = Bsrc + ((size_t)s << 14);
#pragma unroll
      for (int q = 0; q < 4; ++q)
        __builtin_amdgcn_global_load_lds((glb8*)(bs_ + q * 1024),
                                         (lds8*)(Bdst + q * 1024), 16, 0, 0);
    }
    asm volatile("s_waitcnt vmcnt(0)" ::: "memory");
    __syncthreads();                 // A+B landed, all waves ready

    // 3) MFMA phase: A frags read as fp32 + pk2 cvt; B frags direct bf16
#pragma unroll
    for (int kk = 0; kk < 4; ++kk) {
      const int sA = (((kk << 2) | (hi1 << 1)) ^ rs) << 4;  // chunk pair base
      float4 q0 = *(const float4*)(ArdA + sA);
      float4 q1 = *(const float4*)(ArdA + (sA ^ 16));
      float4 q2 = *(const float4*)(ArdB + sA);
      float4 q3 = *(const float4*)(ArdB + (sA ^ 16));
      bf16x8 fa0 = pack8(q0, q1);
      bf16x8 fa1 = pack8(q2, q3);
      const int sB = ((((kk << 1) | hi1)) ^ rs) << 4;
      bf16x8 fb0 = *(const bf16x8*)(Brd0 + sB);
      bf16x8 fb1 = *(const bf16x8*)(Brd1 + sB);
      acc00 = __builtin_amdgcn_mfma_f32_32x32x16_bf16(fa0, fb0, acc00, 0,0,0);
      acc01 = __builtin_amdgcn_mfma_f32_32x32x16_bf16(fa0, fb1, acc01, 0,0,0);
      acc10 = __builtin_amdgcn_mfma_f32_32x32x16_bf16(fa1, fb0, acc10, 0,0,0);
      acc11 = __builtin_amdgcn_mfma_f32_32x32x16_bf16(fa1, fb1, acc11, 0,0,0);
    }
    __syncthreads();                 // reads done before next overwrite
  }

  const int gn0 = bn * 128 + wc + lo5;
  const int gn1 = gn0 + 32;
  const float bv0 = Bv[gn0];
  const float bv1 = Bv[gn1];

#define EPI(ACC, MI, GN, BVAL) do {                                           \
    _Pragma("unroll")                                                         \
    for (int r = 0; r < 16; ++r) {                                            \
      const int mloc = wr + (MI) * 32 + (hi1 << 2) + ((r >> 2) << 3) + (r & 3);\
      Y[(size_t)(bm * 128 + mloc) * NTOT + (GN)] = fast_tanh((ACC)[r] + (BVAL));\
    }                                                                         \
  } while (0)

  EPI(acc00, 0, gn0, bv0);
  EPI(acc01, 0, gn1, bv1);
  EPI(acc10, 1, gn0, bv0);
  EPI(acc11, 1, gn1, bv1);
}

// ---------------- fallback: R1 kernel (146us), used if ws too small ----------
struct Regs {
  float4 a0,a1,a2,a3,a4,a5,a6,a7;
  float4 u0,u1,u2,u3;
  float4 v0,v1,v2,v3;
};

__global__ __launch_bounds__(256, 2)
void hotdd_fallback(const float* __restrict__ X, const float* __restrict__ W,
                    const float* __restrict__ Bv, float* __restrict__ Y) {
  __shared__ char Ab[128 * BK * 2];
  __shared__ char Bb[128 * BK * 2];
  const int d  = blockIdx.x;
  const int bm = ((d >> 5) << 3) | (d & 7);
  const int bn = (d >> 3) & 3;
  const int tid  = threadIdx.x;
  const int lane = tid & 63;
  const int wv   = tid >> 6;
  const int wr   = (wv >> 1) * 64;
  const int wc   = (wv & 1) * 64;
  const int lo5  = lane & 31;
  const int hi1  = lane >> 5;
  const int rs   = lo5 & 7;
  const int am   = tid >> 1;
  const int ah   = tid & 1;
  const int amz  = am & 7;
  const int abase = am * 128;
  const float* Ag = X + (size_t)(bm * 128 + am) * KTOT + ah * 32;
  const int kp = lo5;
  const int ng = wv * 32 + hi1 * 16;
  const float* Bg = W + (size_t)(2 * kp) * NTOT + bn * 128 + ng;

#define LOADR(R, K0) do {                                                     \
    const float* ap_ = Ag + (K0);                                             \
    R.a0 = *(const float4*)(ap_ +  0); R.a1 = *(const float4*)(ap_ +  4);     \
    R.a2 = *(const float4*)(ap_ +  8); R.a3 = *(const float4*)(ap_ + 12);     \
    R.a4 = *(const float4*)(ap_ + 16); R.a5 = *(const float4*)(ap_ + 20);     \
    R.a6 = *(const float4*)(ap_ + 24); R.a7 = *(const float4*)(ap_ + 28);     \
    const float* bp_ = Bg + (size_t)(K0) * NTOT;                              \
    R.u0 = *(const float4*)(bp_ +  0); R.u1 = *(const float4*)(bp_ +  4);     \
    R.u2 = *(const float4*)(bp_ +  8); R.u3 = *(const float4*)(bp_ + 12);     \
    R.v0 = *(const float4*)(bp_ + NTOT +  0); R.v1 = *(const float4*)(bp_ + NTOT +  4); \
    R.v2 = *(const float4*)(bp_ + NTOT +  8); R.v3 = *(const float4*)(bp_ + NTOT + 12); \
  } while (0)

#define ASTF(R, J, P, Q)                                                      \
    *(uint4*)(Ab + abase + (((((ah << 2) + (J)) ^ amz)) << 4)) =              \
      make_uint4(pk2(R.P.x, R.P.y), pk2(R.P.z, R.P.w),                        \
                 pk2(R.Q.x, R.Q.y), pk2(R.Q.z, R.Q.w));
#define BSTF(R, I, UV, C)                                                     \
    *(uint32_t*)(Bb + (ng + (I)) * 128 + ((kp << 2) ^ (((I) & 7) << 4))) =    \
      pk2(R.u##UV.C, R.v##UV.C);

#define STORERF(R) do {                                                       \
    ASTF(R, 0, a0, a1) ASTF(R, 1, a2, a3) ASTF(R, 2, a4, a5) ASTF(R, 3, a6, a7)\
    BSTF(R, 0, 0, x) BSTF(R, 1, 0, y) BSTF(R, 2, 0, z) BSTF(R, 3, 0, w)       \
    BSTF(R, 4, 1, x) BSTF(R, 5, 1, y) BSTF(R, 6, 1, z) BSTF(R, 7, 1, w)       \
    BSTF(R, 8, 2, x) BSTF(R, 9, 2, y) BSTF(R,10, 2, z) BSTF(R,11, 2, w)       \
    BSTF(R,12, 3, x) BSTF(R,13, 3, y) BSTF(R,14, 3, z) BSTF(R,15, 3, w)       \
  } while (0)

  f32x16 acc00 = {}, acc01 = {}, acc10 = {}, acc11 = {};
  const char* Ard0 = Ab + (wr + lo5) * 128;
  const char* Ard1 = Ard0 + 32 * 128;
  const char* Brd0 = Bb + (wc + lo5) * 128;
  const char* Brd1 = Brd0 + 32 * 128;

#define MFMA_PHASE_F() do {                                                   \
    _Pragma("unroll")                                                         \
    for (int kk = 0; kk < 4; ++kk) {                                          \
      const int sb = ((((kk << 1) | hi1) ^ rs) << 4);                         \
      bf16x8 fa0 = *(const bf16x8*)(Ard0 + sb);                               \
      bf16x8 fa1 = *(const bf16x8*)(Ard1 + sb);                               \
      bf16x8 fb0 = *(const bf16x8*)(Brd0 + sb);                               \
      bf16x8 fb1 = *(const bf16x8*)(Brd1 + sb);                               \
      acc00 = __builtin_amdgcn_mfma_f32_32x32x16_bf16(fa0, fb0, acc00, 0,0,0);\
      acc01 = __builtin_amdgcn_mfma_f32_32x32x16_bf16(fa0, fb1, acc01, 0,0,0);\
      acc10 = __builtin_amdgcn_mfma_f32_32x32x16_bf16(fa1, fb0, acc10, 0,0,0);\
      acc11 = __builtin_amdgcn_mfma_f32_32x32x16_bf16(fa1, fb1, acc11, 0,0,0);\
    }                                                                         \
  } while (0)

  Regs r0, r1;
  LOADR(r0, 0);
#pragma unroll 1
  for (int s = 0; s < 8; s += 2) {
    STORERF(r0);
    __syncthreads();
    LOADR(r1, (s + 1) * BK);
    MFMA_PHASE_F();
    __syncthreads();
    STORERF(r1);
    __syncthreads();
    if (s + 2 < 8) LOADR(r0, (s + 2) * BK);
    MFMA_PHASE_F();
    __syncthreads();
  }

  const int gn0 = bn * 128 + wc + lo5;
  const int gn1 = gn0 + 32;
  const float bv0 = Bv[gn0];
  const float bv1 = Bv[gn1];
  EPI(acc00, 0, gn0, bv0);
  EPI(acc01, 0, gn1, bv1);
  EPI(acc10, 1, gn0, bv0);
  EPI(acc11, 1, gn1, bv1);
}

extern "C" void kernel_launch(void* const* d_in, const int* in_sizes, int n_in,
                              void* d_out, int out_size, void* d_ws, size_t ws_size,
                              hipStream_t stream) {
  (void)in_sizes; (void)n_in; (void)out_size;
  const float* X = (const float*)d_in[0];
  const float* W = (const float*)d_in[1];
  const float* b = (const float*)d_in[2];
  float* Y = (float*)d_out;
  if (ws_size >= WS_NEEDED) {
    uint8_t* Wt = (uint8_t*)d_ws;
    hipLaunchKernelGGL(cvtW_kernel, dim3(128),  dim3(256), 0, stream, W, Wt);
    hipLaunchKernelGGL(hotdd_fused, dim3(2048), dim3(256), 0, stream, X, Wt, b, Y);
  } else {
    hipLaunchKernelGGL(hotdd_fallback, dim3(2048), dim3(256), 0, stream, X, W, b, Y);
  }
}

// Round 7
// 88.201 us; speedup vs baseline: 1.1403x; 1.1403x over previous
//
#include <hip/hip_runtime.h>
#include <stdint.h>

// Y = tanh(X @ W + b):  M=65536 (8*64*128), K=512, N=512, all fp32.
// R7: R6's zero-VGPR staging + 2-phase double-buffered pipeline with COUNTED
// vmcnt (T3/T4). BK=32 so dbuf LDS = 2*(16K A-fp32 + 8K B-bf16) = 48KB ->
// 3 blocks/CU. Raw s_barrier (NOT __syncthreads -- that drains vmcnt(0) and
// kills the pipeline). STAGE(t+1) issued before MFMA(t); vmcnt(6) waits only
// for step-t's 6 loads, leaving t+1's in flight across the barrier.
// A: fp32 in LDS, swizzle via pre-swizzled per-lane GLOBAL src (m173), cvt
// to bf16 on fragment read (pk2, overlapped with MFMA).
// B: W pre-converted once to bf16 transposed swizzled image (8KB tiles,
// [r:128][4 slots x 16B], slot = j ^ ((r>>1)&3)); staged linearly.

typedef short bf16x8 __attribute__((ext_vector_type(8)));
typedef float f32x16 __attribute__((ext_vector_type(16)));
typedef uint32_t u32x4 __attribute__((ext_vector_type(4)));

#define KTOT 512
#define NTOT 512
#define WT_BYTES   524288ull      // 512*512*2
#define WS_NEEDED  WT_BYTES

typedef __attribute__((address_space(3))) uint8_t lds8;
typedef __attribute__((address_space(1))) const uint8_t glb8;

__device__ __forceinline__ uint32_t pk2(float a, float b) {
  uint16_t lo = __builtin_bit_cast(uint16_t, (__bf16)a);   // RNE
  uint16_t hi = __builtin_bit_cast(uint16_t, (__bf16)b);
  return (uint32_t)lo | ((uint32_t)hi << 16);
}

__device__ __forceinline__ bf16x8 pack8(float4 a, float4 b) {
  u32x4 t;
  t.x = pk2(a.x, a.y); t.y = pk2(a.z, a.w);
  t.z = pk2(b.x, b.y); t.w = pk2(b.z, b.w);
  return __builtin_bit_cast(bf16x8, t);
}

__device__ __forceinline__ float fast_tanh(float z) {
  float t = __builtin_amdgcn_exp2f(z * 2.8853900817779268f);
  return 1.0f - 2.0f * __builtin_amdgcn_rcpf(t + 1.0f);
}

// ---- pass 1: W fp32 [k][n] -> bf16 transposed swizzled image, BK=32 tiles --
// 64 tiles (bn*16+s) of 8KB: [r:128 rows][4 chunks of 16B].
// Chunk j of row r covers k = s*32 + j*8 .. +7 of column n = bn*128+r;
// stored at slot j ^ ((r>>1)&3).
__global__ __launch_bounds__(256)
void cvtW_kernel(const float* __restrict__ W, uint8_t* __restrict__ Wt) {
  const int c    = blockIdx.x * 256 + threadIdx.x;   // 0..32767
  const int j    = c & 3;
  const int r    = (c >> 2) & 127;
  const int tile = c >> 9;                           // bn*16 + s, 0..63
  const int s    = tile & 15;
  const int bn   = tile >> 4;
  const int n    = bn * 128 + r;
  const int k0   = s * 32 + j * 8;
  const int rk   = (r >> 1) & 3;
  float e[8];
#pragma unroll
  for (int i = 0; i < 8; ++i) e[i] = W[(size_t)(k0 + i) * NTOT + n];
  uint4 v = make_uint4(pk2(e[0], e[1]), pk2(e[2], e[3]),
                       pk2(e[4], e[5]), pk2(e[6], e[7]));
  *(uint4*)(Wt + ((size_t)tile << 13) + (r << 6) + ((j ^ rk) << 4)) = v;
}

// ---------------- pass 2: pipelined GEMM + bias + tanh ----------------
__global__ __launch_bounds__(256, 3)
void hotdd_fused(const float* __restrict__ X, const uint8_t* __restrict__ Wt,
                 const float* __restrict__ Bv, float* __restrict__ Y) {
  __shared__ uint8_t Ab[2][16384];  // [m:128][k:32] fp32, slot c holds chunk c^(r&7)
  __shared__ uint8_t Bb[2][8192];   // [n:128][k:32] bf16, slot c holds chunk c^((r>>1)&3)

  // XCD swizzle: the 4 bn-blocks sharing an X strip -> same XCD, adjacent.
  const int d  = blockIdx.x;
  const int bm = ((d >> 5) << 3) | (d & 7);   // 0..511
  const int bn = (d >> 3) & 3;                // 0..3

  const int tid  = threadIdx.x;
  const int lane = tid & 63;
  const int wv   = tid >> 6;
  const int wr   = (wv >> 1) * 64;
  const int wc   = (wv & 1) * 64;
  const int lo5  = lane & 31;
  const int hi1  = lane >> 5;
  const int rs   = lo5 & 7;              // A read swizzle key (row&7)
  const int bkey = (lo5 >> 1) & 3;       // B read swizzle key ((row>>1)&3)

  // ---- A staging: wave wv owns rows [wv*32, +32); 4 chunks of 1KB = 8 rows.
  // lane l -> row_local l>>3, LDS slot l&7; fetch global chunk (l&7)^(l>>3).
  const int l8  = lane >> 3;
  const int chA = (lane & 7) ^ l8;
  const float* pA = X + (size_t)(bm * 128 + wv * 32 + l8) * KTOT + chA * 4;
  uint8_t* Ad0 = Ab[0] + wv * 4096;   // wave-uniform; HW adds lane*16
  uint8_t* Ad1 = Ab[1] + wv * 4096;

  // ---- B staging: linear copy of pre-swizzled image; 2 chunks of 1KB/wave.
  const uint8_t* pB = Wt + ((size_t)(bn * 16) << 13) + wv * 2048 + lane * 16;
  uint8_t* Bd0 = Bb[0] + wv * 2048;
  uint8_t* Bd1 = Bb[1] + wv * 2048;

#define STAGE(AD, BD, S) do {                                                 \
    const float* as_ = pA + (S) * 32;                                         \
    _Pragma("unroll")                                                         \
    for (int q = 0; q < 4; ++q)                                               \
      __builtin_amdgcn_global_load_lds((glb8*)(as_ + (size_t)q * 8 * KTOT),   \
                                       (lds8*)((AD) + q * 1024), 16, 0, 0);   \
    const uint8_t* bs_ = pB + ((size_t)(S) << 13);                            \
    _Pragma("unroll")                                                         \
    for (int q = 0; q < 2; ++q)                                               \
      __builtin_amdgcn_global_load_lds((glb8*)(bs_ + q * 1024),               \
                                       (lds8*)((BD) + q * 1024), 16, 0, 0);   \
  } while (0)

  f32x16 acc00 = {}, acc01 = {}, acc10 = {}, acc11 = {};

  const uint8_t* Ar0 = Ab[0] + (wr + lo5) * 128;   // frag1 at +4096 (32 rows)
  const uint8_t* Ar1 = Ab[1] + (wr + lo5) * 128;
  const uint8_t* Br0 = Bb[0] + (wc + lo5) * 64;    // frag1 at +2048
  const uint8_t* Br1 = Bb[1] + (wc + lo5) * 64;

#define MFMA_STEP(ARD, BRD) do {                                              \
    _Pragma("unroll")                                                         \
    for (int kk = 0; kk < 2; ++kk) {                                          \
      const int sA = ((((kk << 2) | (hi1 << 1)) ^ rs) << 4);                  \
      float4 q0 = *(const float4*)((ARD) + sA);                               \
      float4 q1 = *(const float4*)((ARD) + (sA ^ 16));                        \
      float4 q2 = *(const float4*)((ARD) + 4096 + sA);                        \
      float4 q3 = *(const float4*)((ARD) + 4096 + (sA ^ 16));                 \
      bf16x8 fa0 = pack8(q0, q1);                                             \
      bf16x8 fa1 = pack8(q2, q3);                                             \
      const int sB = ((((kk << 1) | hi1) ^ bkey) << 4);                       \
      bf16x8 fb0 = *(const bf16x8*)((BRD) + sB);                              \
      bf16x8 fb1 = *(const bf16x8*)((BRD) + 2048 + sB);                       \
      acc00 = __builtin_amdgcn_mfma_f32_32x32x16_bf16(fa0, fb0, acc00, 0,0,0);\
      acc01 = __builtin_amdgcn_mfma_f32_32x32x16_bf16(fa0, fb1, acc01, 0,0,0);\
      acc10 = __builtin_amdgcn_mfma_f32_32x32x16_bf16(fa1, fb0, acc10, 0,0,0);\
      acc11 = __builtin_amdgcn_mfma_f32_32x32x16_bf16(fa1, fb1, acc11, 0,0,0);\
    }                                                                         \
  } while (0)

  STAGE(Ad0, Bd0, 0);

#pragma unroll 1
  for (int t = 0; t < 16; t += 2) {
    // even phase: compute buf0(step t), prefetch step t+1 into buf1
    STAGE(Ad1, Bd1, t + 1);
    asm volatile("s_waitcnt vmcnt(6)" ::: "memory");   // step-t loads landed
    __builtin_amdgcn_s_barrier();
    MFMA_STEP(Ar0, Br0);
    asm volatile("s_waitcnt lgkmcnt(0)" ::: "memory"); // my LDS reads retired
    __builtin_amdgcn_s_barrier();                      // buf0 free to overwrite
    // odd phase: compute buf1(step t+1), prefetch step t+2 into buf0
    if (t + 2 < 16) {
      STAGE(Ad0, Bd0, t + 2);
      asm volatile("s_waitcnt vmcnt(6)" ::: "memory");
    } else {
      asm volatile("s_waitcnt vmcnt(0)" ::: "memory");
    }
    __builtin_amdgcn_s_barrier();
    MFMA_STEP(Ar1, Br1);
    asm volatile("s_waitcnt lgkmcnt(0)" ::: "memory");
    __builtin_amdgcn_s_barrier();
  }

  const int gn0 = bn * 128 + wc + lo5;
  const int gn1 = gn0 + 32;
  const float bv0 = Bv[gn0];
  const float bv1 = Bv[gn1];

#define EPI(ACC, MI, GN, BVAL) do {                                           \
    _Pragma("unroll")                                                         \
    for (int r = 0; r < 16; ++r) {                                            \
      const int mloc = wr + (MI) * 32 + (hi1 << 2) + ((r >> 2) << 3) + (r & 3);\
      Y[(size_t)(bm * 128 + mloc) * NTOT + (GN)] = fast_tanh((ACC)[r] + (BVAL));\
    }                                                                         \
  } while (0)

  EPI(acc00, 0, gn0, bv0);
  EPI(acc01, 0, gn1, bv1);
  EPI(acc10, 1, gn0, bv0);
  EPI(acc11, 1, gn1, bv1);
}

// ---------------- fallback: R1 kernel (146us), used if ws too small ----------
struct Regs {
  float4 a0,a1,a2,a3,a4,a5,a6,a7;
  float4 u0,u1,u2,u3;
  float4 v0,v1,v2,v3;
};

__global__ __launch_bounds__(256, 2)
void hotdd_fallback(const float* __restrict__ X, const float* __restrict__ W,
                    const float* __restrict__ Bv, float* __restrict__ Y) {
  __shared__ char Ab[128 * 64 * 2];
  __shared__ char Bb[128 * 64 * 2];
  const int d  = blockIdx.x;
  const int bm = ((d >> 5) << 3) | (d & 7);
  const int bn = (d >> 3) & 3;
  const int tid  = threadIdx.x;
  const int lane = tid & 63;
  const int wv   = tid >> 6;
  const int wr   = (wv >> 1) * 64;
  const int wc   = (wv & 1) * 64;
  const int lo5  = lane & 31;
  const int hi1  = lane >> 5;
  const int rs   = lo5 & 7;
  const int am   = tid >> 1;
  const int ah   = tid & 1;
  const int amz  = am & 7;
  const int abase = am * 128;
  const float* Ag = X + (size_t)(bm * 128 + am) * KTOT + ah * 32;
  const int kp = lo5;
  const int ng = wv * 32 + hi1 * 16;
  const float* Bg = W + (size_t)(2 * kp) * NTOT + bn * 128 + ng;

#define LOADR(R, K0) do {                                                     \
    const float* ap_ = Ag + (K0);                                             \
    R.a0 = *(const float4*)(ap_ +  0); R.a1 = *(const float4*)(ap_ +  4);     \
    R.a2 = *(const float4*)(ap_ +  8); R.a3 = *(const float4*)(ap_ + 12);     \
    R.a4 = *(const float4*)(ap_ + 16); R.a5 = *(const float4*)(ap_ + 20);     \
    R.a6 = *(const float4*)(ap_ + 24); R.a7 = *(const float4*)(ap_ + 28);     \
    const float* bp_ = Bg + (size_t)(K0) * NTOT;                              \
    R.u0 = *(const float4*)(bp_ +  0); R.u1 = *(const float4*)(bp_ +  4);     \
    R.u2 = *(const float4*)(bp_ +  8); R.u3 = *(const float4*)(bp_ + 12);     \
    R.v0 = *(const float4*)(bp_ + NTOT +  0); R.v1 = *(const float4*)(bp_ + NTOT +  4); \
    R.v2 = *(const float4*)(bp_ + NTOT +  8); R.v3 = *(const float4*)(bp_ + NTOT + 12); \
  } while (0)

#define ASTF(R, J, P, Q)                                                      \
    *(uint4*)(Ab + abase + (((((ah << 2) + (J)) ^ amz)) << 4)) =              \
      make_uint4(pk2(R.P.x, R.P.y), pk2(R.P.z, R.P.w),                        \
                 pk2(R.Q.x, R.Q.y), pk2(R.Q.z, R.Q.w));
#define BSTF(R, I, UV, C)                                                     \
    *(uint32_t*)(Bb + (ng + (I)) * 128 + ((kp << 2) ^ (((I) & 7) << 4))) =    \
      pk2(R.u##UV.C, R.v##UV.C);

#define STORERF(R) do {                                                       \
    ASTF(R, 0, a0, a1) ASTF(R, 1, a2, a3) ASTF(R, 2, a4, a5) ASTF(R, 3, a6, a7)\
    BSTF(R, 0, 0, x) BSTF(R, 1, 0, y) BSTF(R, 2, 0, z) BSTF(R, 3, 0, w)       \
    BSTF(R, 4, 1, x) BSTF(R, 5, 1, y) BSTF(R, 6, 1, z) BSTF(R, 7, 1, w)       \
    BSTF(R, 8, 2, x) BSTF(R, 9, 2, y) BSTF(R,10, 2, z) BSTF(R,11, 2, w)       \
    BSTF(R,12, 3, x) BSTF(R,13, 3, y) BSTF(R,14, 3, z) BSTF(R,15, 3, w)       \
  } while (0)

  f32x16 acc00 = {}, acc01 = {}, acc10 = {}, acc11 = {};
  const char* Ard0 = Ab + (wr + lo5) * 128;
  const char* Ard1 = Ard0 + 32 * 128;
  const char* Brd0 = Bb + (wc + lo5) * 128;
  const char* Brd1 = Brd0 + 32 * 128;

#define MFMA_PHASE_F() do {                                                   \
    _Pragma("unroll")                                                         \
    for (int kk = 0; kk < 4; ++kk) {                                          \
      const int sb = ((((kk << 1) | hi1) ^ rs) << 4);                         \
      bf16x8 fa0 = *(const bf16x8*)(Ard0 + sb);                               \
      bf16x8 fa1 = *(const bf16x8*)(Ard1 + sb);                               \
      bf16x8 fb0 = *(const bf16x8*)(Brd0 + sb);                               \
      bf16x8 fb1 = *(const bf16x8*)(Brd1 + sb);                               \
      acc00 = __builtin_amdgcn_mfma_f32_32x32x16_bf16(fa0, fb0, acc00, 0,0,0);\
      acc01 = __builtin_amdgcn_mfma_f32_32x32x16_bf16(fa0, fb1, acc01, 0,0,0);\
      acc10 = __builtin_amdgcn_mfma_f32_32x32x16_bf16(fa1, fb0, acc10, 0,0,0);\
      acc11 = __builtin_amdgcn_mfma_f32_32x32x16_bf16(fa1, fb1, acc11, 0,0,0);\
    }                                                                         \
  } while (0)

  Regs r0, r1;
  LOADR(r0, 0);
#pragma unroll 1
  for (int s = 0; s < 8; s += 2) {
    STORERF(r0);
    __syncthreads();
    LOADR(r1, (s + 1) * 64);
    MFMA_PHASE_F();
    __syncthreads();
    STORERF(r1);
    __syncthreads();
    if (s + 2 < 8) LOADR(r0, (s + 2) * 64);
    MFMA_PHASE_F();
    __syncthreads();
  }

  const int gn0 = bn * 128 + wc + lo5;
  const int gn1 = gn0 + 32;
  const float bv0 = Bv[gn0];
  const float bv1 = Bv[gn1];
  EPI(acc00, 0, gn0, bv0);
  EPI(acc01, 0, gn1, bv1);
  EPI(acc10, 1, gn0, bv0);
  EPI(acc11, 1, gn1, bv1);
}

extern "C" void kernel_launch(void* const* d_in, const int* in_sizes, int n_in,
                              void* d_out, int out_size, void* d_ws, size_t ws_size,
                              hipStream_t stream) {
  (void)in_sizes; (void)n_in; (void)out_size;
  const float* X = (const float*)d_in[0];
  const float* W = (const float*)d_in[1];
  const float* b = (const float*)d_in[2];
  float* Y = (float*)d_out;
  if (ws_size >= WS_NEEDED) {
    uint8_t* Wt = (uint8_t*)d_ws;
    hipLaunchKernelGGL(cvtW_kernel, dim3(128),  dim3(256), 0, stream, W, Wt);
    hipLaunchKernelGGL(hotdd_fused, dim3(2048), dim3(256), 0, stream, X, Wt, b, Y);
  } else {
    hipLaunchKernelGGL(hotdd_fallback, dim3(2048), dim3(256), 0, stream, X, W, b, Y);
  }
}

// Round 8
// 84.265 us; speedup vs baseline: 1.1935x; 1.0467x over previous
//
#include <hip/hip_runtime.h>
#include <stdint.h>

// Y = tanh(X @ W + b):  M=65536 (8*64*128), K=512, N=512, all fp32.
// R8: single fused pass, BK=32, one barrier/step.
//  - A: depth-1 reg prefetch (16 fp32/lane), 8 pk2 -> 2 ds_write_b128 of bf16.
//    LDS A-tile [128][32] bf16 = 8KB/buf.
//  - B: pre-swizzled bf16 image (cvtW) staged via global_load_lds (0 VGPR).
//  - Swizzle (both A and B, 64B rows): slot = c ^ (((r>>1)^(r>>3))&3).
//    R7's keys (r&7 on 128B rows, (r>>1)&3) left 4-way conflicts (6.3M cyc);
//    this one is granule-uniform (verified by enumeration) -> conflict-free.
//  - VGPR+AGPR budget ~110 <= 128 -> 4 blocks/CU (R7: 132 -> rounded to Occ 28%).
//  - Step: barrier -> issue B-glds(t+1)+A-loads(t+1) -> MFMA(t) -> vmcnt(0)
//    -> cvt+write A(t+1) -> lgkmcnt(0) -> barrier.  Loads fly over MFMA phase;
//    16 desynced waves/CU absorb the residual.

typedef short bf16x8 __attribute__((ext_vector_type(8)));
typedef float f32x16 __attribute__((ext_vector_type(16)));

#define KTOT 512
#define NTOT 512
#define WT_BYTES   524288ull      // 512*512*2
#define WS_NEEDED  WT_BYTES

typedef __attribute__((address_space(3))) uint8_t lds8;
typedef __attribute__((address_space(1))) const uint8_t glb8;

__device__ __forceinline__ uint32_t pk2(float a, float b) {
  uint16_t lo = __builtin_bit_cast(uint16_t, (__bf16)a);   // RNE
  uint16_t hi = __builtin_bit_cast(uint16_t, (__bf16)b);
  return (uint32_t)lo | ((uint32_t)hi << 16);
}

__device__ __forceinline__ float fast_tanh(float z) {
  float t = __builtin_amdgcn_exp2f(z * 2.8853900817779268f);
  return 1.0f - 2.0f * __builtin_amdgcn_rcpf(t + 1.0f);
}

__device__ __forceinline__ int swz4(int r) { return ((r >> 1) ^ (r >> 3)) & 3; }

// ---- pass 1: W fp32 [k][n] -> bf16 transposed swizzled image, BK=32 tiles --
// 64 tiles (bn*16+s) of 8KB: [r:128 rows][4 slots x 16B].
// Chunk j of row r covers k = s*32 + j*8 ..+7 of col n = bn*128+r;
// stored at slot j ^ swz4(r).
__global__ __launch_bounds__(256)
void cvtW_kernel(const float* __restrict__ W, uint8_t* __restrict__ Wt) {
  const int c    = blockIdx.x * 256 + threadIdx.x;   // 0..32767
  const int j    = c & 3;
  const int r    = (c >> 2) & 127;
  const int tile = c >> 9;                           // bn*16 + s, 0..63
  const int s    = tile & 15;
  const int bn   = tile >> 4;
  const int n    = bn * 128 + r;
  const int k0   = s * 32 + j * 8;
  float e[8];
#pragma unroll
  for (int i = 0; i < 8; ++i) e[i] = W[(size_t)(k0 + i) * NTOT + n];
  uint4 v = make_uint4(pk2(e[0], e[1]), pk2(e[2], e[3]),
                       pk2(e[4], e[5]), pk2(e[6], e[7]));
  *(uint4*)(Wt + ((size_t)tile << 13) + (r << 6) + ((j ^ swz4(r)) << 4)) = v;
}

// ---------------- pass 2: fused GEMM + bias + tanh ----------------
__global__ __launch_bounds__(256, 4)
void hotdd_fused(const float* __restrict__ X, const uint8_t* __restrict__ Wt,
                 const float* __restrict__ Bv, float* __restrict__ Y) {
  __shared__ uint8_t Ab0[8192], Ab1[8192], Bb0[8192], Bb1[8192];

  // XCD swizzle: the 4 bn-blocks sharing an X strip -> same XCD, adjacent.
  const int d  = blockIdx.x;
  const int bm = ((d >> 5) << 3) | (d & 7);   // 0..511
  const int bn = (d >> 3) & 3;                // 0..3

  const int tid  = threadIdx.x;
  const int lane = tid & 63;
  const int wv   = tid >> 6;
  const int wr   = (wv >> 1) * 64;
  const int wc   = (wv & 1) * 64;
  const int lo5  = lane & 31;
  const int hi1  = lane >> 5;

  // ---- A staging: lane -> row arow = wv*32 + (lane>>1), k-half ahalf.
  const int arow  = wv * 32 + (lane >> 1);
  const int ahalf = lane & 1;
  const float* pA = X + (size_t)(bm * 128 + arow) * KTOT + ahalf * 16;
  const int ak  = swz4(arow);
  const int aw0 = arow * 64 + ((((ahalf << 1) | 0) ^ ak) << 4);
  const int aw1 = arow * 64 + ((((ahalf << 1) | 1) ^ ak) << 4);

  // ---- B staging: wave wv copies bytes [wv*2048, +2048) of the 8KB tile.
  const uint8_t* pB = Wt + ((size_t)(bn * 16) << 13) + wv * 2048 + lane * 16;
  uint8_t* Bd0 = Bb0 + wv * 2048;   // wave-uniform; HW adds lane*16
  uint8_t* Bd1 = Bb1 + wv * 2048;

  // ---- fragment read offsets (64B rows, swizzled slots)
  const int rA0 = wr + lo5, rA1 = rA0 + 32;
  const int rB0 = wc + lo5, rB1 = rB0 + 32;
  const int oA0 = rA0 * 64, oA1 = rA1 * 64;
  const int oB0 = rB0 * 64, oB1 = rB1 * 64;
  const int kA0 = swz4(rA0), kA1 = swz4(rA1);
  const int kB0 = swz4(rB0), kB1 = swz4(rB1);

  float4 pa0, pa1, pa2, pa3;
  f32x16 acc00 = {}, acc01 = {}, acc10 = {}, acc11 = {};

#define BGLDS(BD, S) do {                                                     \
    const uint8_t* bs_ = pB + ((size_t)(S) << 13);                            \
    __builtin_amdgcn_global_load_lds((glb8*)bs_, (lds8*)(BD), 16, 0, 0);      \
    __builtin_amdgcn_global_load_lds((glb8*)(bs_ + 1024),                     \
                                     (lds8*)((BD) + 1024), 16, 0, 0);         \
  } while (0)

#define LOADA(S) do {                                                         \
    const float* ap_ = pA + (S) * 32;                                         \
    pa0 = *(const float4*)(ap_ + 0);  pa1 = *(const float4*)(ap_ + 4);        \
    pa2 = *(const float4*)(ap_ + 8);  pa3 = *(const float4*)(ap_ + 12);       \
  } while (0)

#define CVTA(AB) do {                                                         \
    *(uint4*)((AB) + aw0) = make_uint4(pk2(pa0.x, pa0.y), pk2(pa0.z, pa0.w),  \
                                       pk2(pa1.x, pa1.y), pk2(pa1.z, pa1.w)); \
    *(uint4*)((AB) + aw1) = make_uint4(pk2(pa2.x, pa2.y), pk2(pa2.z, pa2.w),  \
                                       pk2(pa3.x, pa3.y), pk2(pa3.z, pa3.w)); \
  } while (0)

#define MFMA_STEP(AB, BB) do {                                                \
    _Pragma("unroll")                                                         \
    for (int kk = 0; kk < 2; ++kk) {                                          \
      const int c_ = (kk << 1) | hi1;                                         \
      bf16x8 fa0 = *(const bf16x8*)((AB) + oA0 + ((c_ ^ kA0) << 4));          \
      bf16x8 fa1 = *(const bf16x8*)((AB) + oA1 + ((c_ ^ kA1) << 4));          \
      bf16x8 fb0 = *(const bf16x8*)((BB) + oB0 + ((c_ ^ kB0) << 4));          \
      bf16x8 fb1 = *(const bf16x8*)((BB) + oB1 + ((c_ ^ kB1) << 4));          \
      acc00 = __builtin_amdgcn_mfma_f32_32x32x16_bf16(fa0, fb0, acc00, 0,0,0);\
      acc01 = __builtin_amdgcn_mfma_f32_32x32x16_bf16(fa0, fb1, acc01, 0,0,0);\
      acc10 = __builtin_amdgcn_mfma_f32_32x32x16_bf16(fa1, fb0, acc10, 0,0,0);\
      acc11 = __builtin_amdgcn_mfma_f32_32x32x16_bf16(fa1, fb1, acc11, 0,0,0);\
    }                                                                         \
  } while (0)

#define VMCNT0()  asm volatile("s_waitcnt vmcnt(0)" ::: "memory")
#define LGKM0()   asm volatile("s_waitcnt lgkmcnt(0)" ::: "memory")

  // ---- prologue: stage step 0
  BGLDS(Bd0, 0);
  LOADA(0);
  VMCNT0();
  CVTA(Ab0);
  LGKM0();
  __builtin_amdgcn_s_barrier();

  // ---- main loop: each half = compute t, prep t+1. 1 barrier per step.
#pragma unroll 1
  for (int t = 0; t < 14; t += 2) {
    BGLDS(Bd1, t + 1);
    LOADA(t + 1);
    MFMA_STEP(Ab0, Bb0);          // step t
    VMCNT0();                     // A(t+1) regs + B(t+1) glds landed
    CVTA(Ab1);
    LGKM0();                      // writes (and my reads) drained
    __builtin_amdgcn_s_barrier();

    BGLDS(Bd0, t + 2);
    LOADA(t + 2);
    MFMA_STEP(Ab1, Bb1);          // step t+1
    VMCNT0();
    CVTA(Ab0);
    LGKM0();
    __builtin_amdgcn_s_barrier();
  }
  // tail: t=14 computes from buf0, preps 15; t=15 computes from buf1
  BGLDS(Bd1, 15);
  LOADA(15);
  MFMA_STEP(Ab0, Bb0);            // step 14
  VMCNT0();
  CVTA(Ab1);
  LGKM0();
  __builtin_amdgcn_s_barrier();
  MFMA_STEP(Ab1, Bb1);            // step 15

  // ---- epilogue: bias + tanh + fp32 store
  const int gn0 = bn * 128 + wc + lo5;
  const int gn1 = gn0 + 32;
  const float bv0 = Bv[gn0];
  const float bv1 = Bv[gn1];

#define EPI(ACC, MI, GN, BVAL) do {                                           \
    _Pragma("unroll")                                                         \
    for (int r = 0; r < 16; ++r) {                                            \
      const int mloc = wr + (MI) * 32 + (hi1 << 2) + ((r >> 2) << 3) + (r & 3);\
      Y[(size_t)(bm * 128 + mloc) * NTOT + (GN)] = fast_tanh((ACC)[r] + (BVAL));\
    }                                                                         \
  } while (0)

  EPI(acc00, 0, gn0, bv0);
  EPI(acc01, 0, gn1, bv1);
  EPI(acc10, 1, gn0, bv0);
  EPI(acc11, 1, gn1, bv1);
}

// ---------------- fallback: R1 kernel (146us), used if ws too small ----------
struct Regs {
  float4 a0,a1,a2,a3,a4,a5,a6,a7;
  float4 u0,u1,u2,u3;
  float4 v0,v1,v2,v3;
};

__global__ __launch_bounds__(256, 2)
void hotdd_fallback(const float* __restrict__ X, const float* __restrict__ W,
                    const float* __restrict__ Bv, float* __restrict__ Y) {
  __shared__ char Ab[128 * 64 * 2];
  __shared__ char Bb[128 * 64 * 2];
  const int d  = blockIdx.x;
  const int bm = ((d >> 5) << 3) | (d & 7);
  const int bn = (d >> 3) & 3;
  const int tid  = threadIdx.x;
  const int lane = tid & 63;
  const int wv   = tid >> 6;
  const int wr   = (wv >> 1) * 64;
  const int wc   = (wv & 1) * 64;
  const int lo5  = lane & 31;
  const int hi1  = lane >> 5;
  const int rs   = lo5 & 7;
  const int am   = tid >> 1;
  const int ah   = tid & 1;
  const int amz  = am & 7;
  const int abase = am * 128;
  const float* Ag = X + (size_t)(bm * 128 + am) * KTOT + ah * 32;
  const int kp = lo5;
  const int ng = wv * 32 + hi1 * 16;
  const float* Bg = W + (size_t)(2 * kp) * NTOT + bn * 128 + ng;

#define LOADR(R, K0) do {                                                     \
    const float* ap_ = Ag + (K0);                                             \
    R.a0 = *(const float4*)(ap_ +  0); R.a1 = *(const float4*)(ap_ +  4);     \
    R.a2 = *(const float4*)(ap_ +  8); R.a3 = *(const float4*)(ap_ + 12);     \
    R.a4 = *(const float4*)(ap_ + 16); R.a5 = *(const float4*)(ap_ + 20);     \
    R.a6 = *(const float4*)(ap_ + 24); R.a7 = *(const float4*)(ap_ + 28);     \
    const float* bp_ = Bg + (size_t)(K0) * NTOT;                              \
    R.u0 = *(const float4*)(bp_ +  0); R.u1 = *(const float4*)(bp_ +  4);     \
    R.u2 = *(const float4*)(bp_ +  8); R.u3 = *(const float4*)(bp_ + 12);     \
    R.v0 = *(const float4*)(bp_ + NTOT +  0); R.v1 = *(const float4*)(bp_ + NTOT +  4); \
    R.v2 = *(const float4*)(bp_ + NTOT +  8); R.v3 = *(const float4*)(bp_ + NTOT + 12); \
  } while (0)

#define ASTF(R, J, P, Q)                                                      \
    *(uint4*)(Ab + abase + (((((ah << 2) + (J)) ^ amz)) << 4)) =              \
      make_uint4(pk2(R.P.x, R.P.y), pk2(R.P.z, R.P.w),                        \
                 pk2(R.Q.x, R.Q.y), pk2(R.Q.z, R.Q.w));
#define BSTF(R, I, UV, C)                                                     \
    *(uint32_t*)(Bb + (ng + (I)) * 128 + ((kp << 2) ^ (((I) & 7) << 4))) =    \
      pk2(R.u##UV.C, R.v##UV.C);

#define STORERF(R) do {                                                       \
    ASTF(R, 0, a0, a1) ASTF(R, 1, a2, a3) ASTF(R, 2, a4, a5) ASTF(R, 3, a6, a7)\
    BSTF(R, 0, 0, x) BSTF(R, 1, 0, y) BSTF(R, 2, 0, z) BSTF(R, 3, 0, w)       \
    BSTF(R, 4, 1, x) BSTF(R, 5, 1, y) BSTF(R, 6, 1, z) BSTF(R, 7, 1, w)       \
    BSTF(R, 8, 2, x) BSTF(R, 9, 2, y) BSTF(R,10, 2, z) BSTF(R,11, 2, w)       \
    BSTF(R,12, 3, x) BSTF(R,13, 3, y) BSTF(R,14, 3, z) BSTF(R,15, 3, w)       \
  } while (0)

  f32x16 acc00 = {}, acc01 = {}, acc10 = {}, acc11 = {};
  const char* Ard0 = Ab + (wr + lo5) * 128;
  const char* Ard1 = Ard0 + 32 * 128;
  const char* Brd0 = Bb + (wc + lo5) * 128;
  const char* Brd1 = Brd0 + 32 * 128;

#define MFMA_PHASE_F() do {                                                   \
    _Pragma("unroll")                                                         \
    for (int kk = 0; kk < 4; ++kk) {                                          \
      const int sb = ((((kk << 1) | hi1) ^ rs) << 4);                         \
      bf16x8 fa0 = *(const bf16x8*)(Ard0 + sb);                               \
      bf16x8 fa1 = *(const bf16x8*)(Ard1 + sb);                               \
      bf16x8 fb0 = *(const bf16x8*)(Brd0 + sb);                               \
      bf16x8 fb1 = *(const bf16x8*)(Brd1 + sb);                               \
      acc00 = __builtin_amdgcn_mfma_f32_32x32x16_bf16(fa0, fb0, acc00, 0,0,0);\
      acc01 = __builtin_amdgcn_mfma_f32_32x32x16_bf16(fa0, fb1, acc01, 0,0,0);\
      acc10 = __builtin_amdgcn_mfma_f32_32x32x16_bf16(fa1, fb0, acc10, 0,0,0);\
      acc11 = __builtin_amdgcn_mfma_f32_32x32x16_bf16(fa1, fb1, acc11, 0,0,0);\
    }                                                                         \
  } while (0)

  Regs r0, r1;
  LOADR(r0, 0);
#pragma unroll 1
  for (int s = 0; s < 8; s += 2) {
    STORERF(r0);
    __syncthreads();
    LOADR(r1, (s + 1) * 64);
    MFMA_PHASE_F();
    __syncthreads();
    STORERF(r1);
    __syncthreads();
    if (s + 2 < 8) LOADR(r0, (s + 2) * 64);
    MFMA_PHASE_F();
    __syncthreads();
  }

  const int gn0 = bn * 128 + wc + lo5;
  const int gn1 = gn0 + 32;
  const float bv0 = Bv[gn0];
  const float bv1 = Bv[gn1];
  EPI(acc00, 0, gn0, bv0);
  EPI(acc01, 0, gn1, bv1);
  EPI(acc10, 1, gn0, bv0);
  EPI(acc11, 1, gn1, bv1);
}

extern "C" void kernel_launch(void* const* d_in, const int* in_sizes, int n_in,
                              void* d_out, int out_size, void* d_ws, size_t ws_size,
                              hipStream_t stream) {
  (void)in_sizes; (void)n_in; (void)out_size;
  const float* X = (const float*)d_in[0];
  const float* W = (const float*)d_in[1];
  const float* b = (const float*)d_in[2];
  float* Y = (float*)d_out;
  if (ws_size >= WS_NEEDED) {
    uint8_t* Wt = (uint8_t*)d_ws;
    hipLaunchKernelGGL(cvtW_kernel, dim3(128),  dim3(256), 0, stream, W, Wt);
    hipLaunchKernelGGL(hotdd_fused, dim3(2048), dim3(256), 0, stream, X, Wt, b, Y);
  } else {
    hipLaunchKernelGGL(hotdd_fallback, dim3(2048), dim3(256), 0, stream, X, W, b, Y);
  }
}

// Round 9
// 78.392 us; speedup vs baseline: 1.2829x; 1.0749x over previous
//
#include <hip/hip_runtime.h>
#include <stdint.h>

// Y = tanh(X @ W + b):  M=65536 (8*64*128), K=512, N=512, all fp32.
// R9: counted-vmcnt pipeline (T3/T4), BK=32, depth-2 A-reg prefetch.
// Queue discipline per step t (simulated, order pinned by asm separators):
//   entry queue = [B(t):2, A(t+1):4]
//   vmcnt(4)  -> B(t) landed  (BEFORE barrier: per-wave guarantee + barrier
//                              => cross-wave glds visibility, R8's race-free rule)
//   s_barrier
//   BGLDS(t+1 -> bufO.B)   ; LOADA(t+2 -> rFar)
//   MFMA(t) on bufC
//   vmcnt(6)  -> A(t+1) landed, leaves [B(t+1):2, A(t+2):4] in flight
//   CVTA(rNear -> bufO.A)  ; lgkmcnt(0)
// Covers: B ~1 step (W is L2-hot), A ~1.7 steps (> 900cy HBM). Never vmcnt(0)
// in the loop. VGPR ~70 + 64 AGPR -> __launch_bounds__(256,3) (no spill;
// R2/R3 spilled at demand ~190 under cap 128 -- here ~134 under cap ~170).

typedef short bf16x8 __attribute__((ext_vector_type(8)));
typedef float f32x16 __attribute__((ext_vector_type(16)));

#define KTOT 512
#define NTOT 512
#define WT_BYTES   524288ull      // 512*512*2
#define WS_NEEDED  WT_BYTES

typedef __attribute__((address_space(3))) uint8_t lds8;
typedef __attribute__((address_space(1))) const uint8_t glb8;

__device__ __forceinline__ uint32_t pk2(float a, float b) {
  uint16_t lo = __builtin_bit_cast(uint16_t, (__bf16)a);   // RNE
  uint16_t hi = __builtin_bit_cast(uint16_t, (__bf16)b);
  return (uint32_t)lo | ((uint32_t)hi << 16);
}

__device__ __forceinline__ float fast_tanh(float z) {
  float t = __builtin_amdgcn_exp2f(z * 2.8853900817779268f);
  return 1.0f - 2.0f * __builtin_amdgcn_rcpf(t + 1.0f);
}

__device__ __forceinline__ int swz4(int r) { return ((r >> 1) ^ (r >> 3)) & 3; }

// ---- pass 1: W fp32 [k][n] -> bf16 transposed swizzled image, BK=32 tiles --
// 64 tiles (bn*16+s) of 8KB: [r:128 rows][4 slots x 16B]; chunk j of row r
// (k = s*32 + j*8 ..+7, col n = bn*128+r) stored at slot j ^ swz4(r).
__global__ __launch_bounds__(256)
void cvtW_kernel(const float* __restrict__ W, uint8_t* __restrict__ Wt) {
  const int c    = blockIdx.x * 256 + threadIdx.x;   // 0..32767
  const int j    = c & 3;
  const int r    = (c >> 2) & 127;
  const int tile = c >> 9;                           // bn*16 + s, 0..63
  const int s    = tile & 15;
  const int bn   = tile >> 4;
  const int n    = bn * 128 + r;
  const int k0   = s * 32 + j * 8;
  float e[8];
#pragma unroll
  for (int i = 0; i < 8; ++i) e[i] = W[(size_t)(k0 + i) * NTOT + n];
  uint4 v = make_uint4(pk2(e[0], e[1]), pk2(e[2], e[3]),
                       pk2(e[4], e[5]), pk2(e[6], e[7]));
  *(uint4*)(Wt + ((size_t)tile << 13) + (r << 6) + ((j ^ swz4(r)) << 4)) = v;
}

// ---------------- pass 2: fused GEMM + bias + tanh ----------------
__global__ __launch_bounds__(256, 3)
void hotdd_fused(const float* __restrict__ X, const uint8_t* __restrict__ Wt,
                 const float* __restrict__ Bv, float* __restrict__ Y) {
  __shared__ uint8_t Ab0[8192], Ab1[8192], Bb0[8192], Bb1[8192];

  // XCD swizzle: the 4 bn-blocks sharing an X strip -> same XCD, adjacent.
  const int d  = blockIdx.x;
  const int bm = ((d >> 5) << 3) | (d & 7);   // 0..511
  const int bn = (d >> 3) & 3;                // 0..3

  const int tid  = threadIdx.x;
  const int lane = tid & 63;
  const int wv   = tid >> 6;
  const int wr   = (wv >> 1) * 64;
  const int wc   = (wv & 1) * 64;
  const int lo5  = lane & 31;
  const int hi1  = lane >> 5;

  // ---- A staging map: lane -> row arow = wv*32 + (lane>>1), k-half ahalf.
  const int arow  = wv * 32 + (lane >> 1);
  const int ahalf = lane & 1;
  const float* pA = X + (size_t)(bm * 128 + arow) * KTOT + ahalf * 16;
  const int ak  = swz4(arow);
  const int aw0 = arow * 64 + ((((ahalf << 1) | 0) ^ ak) << 4);
  const int aw1 = arow * 64 + ((((ahalf << 1) | 1) ^ ak) << 4);

  // ---- B staging: wave wv copies bytes [wv*2048, +2048) of the 8KB tile.
  const uint8_t* pB = Wt + ((size_t)(bn * 16) << 13) + wv * 2048 + lane * 16;
  uint8_t* Bd0 = Bb0 + wv * 2048;   // wave-uniform; HW adds lane*16
  uint8_t* Bd1 = Bb1 + wv * 2048;

  // ---- fragment read offsets (64B rows, swizzled slots)
  const int rA0 = wr + lo5, rA1 = rA0 + 32;
  const int rB0 = wc + lo5, rB1 = rB0 + 32;
  const int oA0 = rA0 * 64, oA1 = rA1 * 64;
  const int oB0 = rB0 * 64, oB1 = rB1 * 64;
  const int kA0 = swz4(rA0), kA1 = swz4(rA1);
  const int kB0 = swz4(rB0), kB1 = swz4(rB1);

  float4 ra0, ra1, ra2, ra3;        // A-prefetch reg set a
  float4 rb0, rb1, rb2, rb3;        // A-prefetch reg set b
  f32x16 acc00 = {}, acc01 = {}, acc10 = {}, acc11 = {};

#define SEP() asm volatile("" ::: "memory")
#define VM(N)  asm volatile("s_waitcnt vmcnt(" #N ")" ::: "memory")
#define LGKM0() asm volatile("s_waitcnt lgkmcnt(0)" ::: "memory")

#define BGLDS(BD, S) do {                                                     \
    const uint8_t* bs_ = pB + ((size_t)(S) << 13);                            \
    __builtin_amdgcn_global_load_lds((glb8*)bs_, (lds8*)(BD), 16, 0, 0);      \
    __builtin_amdgcn_global_load_lds((glb8*)(bs_ + 1024),                     \
                                     (lds8*)((BD) + 1024), 16, 0, 0);         \
    SEP();                                                                    \
  } while (0)

#define LOADA(R0, R1, R2, R3, S) do {                                         \
    const float* ap_ = pA + (S) * 32;                                         \
    R0 = *(const float4*)(ap_ + 0);  R1 = *(const float4*)(ap_ + 4);          \
    R2 = *(const float4*)(ap_ + 8);  R3 = *(const float4*)(ap_ + 12);         \
    SEP();                                                                    \
  } while (0)

#define CVTA(R0, R1, R2, R3, AB) do {                                         \
    *(uint4*)((AB) + aw0) = make_uint4(pk2(R0.x, R0.y), pk2(R0.z, R0.w),      \
                                       pk2(R1.x, R1.y), pk2(R1.z, R1.w));     \
    *(uint4*)((AB) + aw1) = make_uint4(pk2(R2.x, R2.y), pk2(R2.z, R2.w),      \
                                       pk2(R3.x, R3.y), pk2(R3.z, R3.w));     \
  } while (0)

#define MFMA_STEP(AB, BB) do {                                                \
    _Pragma("unroll")                                                         \
    for (int kk = 0; kk < 2; ++kk) {                                          \
      const int c_ = (kk << 1) | hi1;                                         \
      bf16x8 fa0 = *(const bf16x8*)((AB) + oA0 + ((c_ ^ kA0) << 4));          \
      bf16x8 fa1 = *(const bf16x8*)((AB) + oA1 + ((c_ ^ kA1) << 4));          \
      bf16x8 fb0 = *(const bf16x8*)((BB) + oB0 + ((c_ ^ kB0) << 4));          \
      bf16x8 fb1 = *(const bf16x8*)((BB) + oB1 + ((c_ ^ kB1) << 4));          \
      acc00 = __builtin_amdgcn_mfma_f32_32x32x16_bf16(fa0, fb0, acc00, 0,0,0);\
      acc01 = __builtin_amdgcn_mfma_f32_32x32x16_bf16(fa0, fb1, acc01, 0,0,0);\
      acc10 = __builtin_amdgcn_mfma_f32_32x32x16_bf16(fa1, fb0, acc10, 0,0,0);\
      acc11 = __builtin_amdgcn_mfma_f32_32x32x16_bf16(fa1, fb1, acc11, 0,0,0);\
    }                                                                         \
  } while (0)

  // ---- prologue: queue becomes [A(0):4, B(0):2, A(1):4]
  LOADA(ra0, ra1, ra2, ra3, 0);
  BGLDS(Bd0, 0);
  LOADA(rb0, rb1, rb2, rb3, 1);
  VM(6);                            // A(0) landed
  CVTA(ra0, ra1, ra2, ra3, Ab0);
  LGKM0();
  // entering loop: queue = [B(0):2, A(1):4]  (steady shape)

  // ---- main loop t = 0..13, two steps per iteration (buffers/regs by parity)
#pragma unroll 1
  for (int t = 0; t < 14; t += 2) {
    // even step t: compute buf0, prep buf1; rNear=rb=A(t+1), rFar=ra
    VM(4);                          // B(t) landed (pre-barrier!)
    __builtin_amdgcn_s_barrier();
    BGLDS(Bd1, t + 1);
    LOADA(ra0, ra1, ra2, ra3, t + 2);
    MFMA_STEP(Ab0, Bb0);
    VM(6);                          // A(t+1) landed; [B(t+1):2, A(t+2):4] fly
    CVTA(rb0, rb1, rb2, rb3, Ab1);
    LGKM0();
    // odd step t+1: compute buf1, prep buf0; rNear=ra=A(t+2), rFar=rb
    VM(4);                          // B(t+1) landed
    __builtin_amdgcn_s_barrier();
    BGLDS(Bd0, t + 2);
    LOADA(rb0, rb1, rb2, rb3, t + 3);
    MFMA_STEP(Ab1, Bb1);
    VM(6);                          // A(t+2) landed
    CVTA(ra0, ra1, ra2, ra3, Ab0);
    LGKM0();
  }

  // ---- tail: t=14 (no A(16) to load), t=15 (no prep at all)
  VM(4);                            // B(14) landed
  __builtin_amdgcn_s_barrier();
  BGLDS(Bd1, 15);
  MFMA_STEP(Ab0, Bb0);              // step 14
  VM(2);                            // A(15) landed (leaves B(15):2)
  CVTA(rb0, rb1, rb2, rb3, Ab1);
  LGKM0();
  VM(0);                            // B(15) landed
  __builtin_amdgcn_s_barrier();
  MFMA_STEP(Ab1, Bb1);              // step 15

  // ---- epilogue: bias + tanh + fp32 store
  const int gn0 = bn * 128 + wc + lo5;
  const int gn1 = gn0 + 32;
  const float bv0 = Bv[gn0];
  const float bv1 = Bv[gn1];

#define EPI(ACC, MI, GN, BVAL) do {                                           \
    _Pragma("unroll")                                                         \
    for (int r = 0; r < 16; ++r) {                                            \
      const int mloc = wr + (MI) * 32 + (hi1 << 2) + ((r >> 2) << 3) + (r & 3);\
      Y[(size_t)(bm * 128 + mloc) * NTOT + (GN)] = fast_tanh((ACC)[r] + (BVAL));\
    }                                                                         \
  } while (0)

  EPI(acc00, 0, gn0, bv0);
  EPI(acc01, 0, gn1, bv1);
  EPI(acc10, 1, gn0, bv0);
  EPI(acc11, 1, gn1, bv1);
}

// ---------------- fallback: R1 kernel (146us), used if ws too small ----------
struct Regs {
  float4 a0,a1,a2,a3,a4,a5,a6,a7;
  float4 u0,u1,u2,u3;
  float4 v0,v1,v2,v3;
};

__global__ __launch_bounds__(256, 2)
void hotdd_fallback(const float* __restrict__ X, const float* __restrict__ W,
                    const float* __restrict__ Bv, float* __restrict__ Y) {
  __shared__ char Ab[128 * 64 * 2];
  __shared__ char Bb[128 * 64 * 2];
  const int d  = blockIdx.x;
  const int bm = ((d >> 5) << 3) | (d & 7);
  const int bn = (d >> 3) & 3;
  const int tid  = threadIdx.x;
  const int lane = tid & 63;
  const int wv   = tid >> 6;
  const int wr   = (wv >> 1) * 64;
  const int wc   = (wv & 1) * 64;
  const int lo5  = lane & 31;
  const int hi1  = lane >> 5;
  const int rs   = lo5 & 7;
  const int am   = tid >> 1;
  const int ah   = tid & 1;
  const int amz  = am & 7;
  const int abase = am * 128;
  const float* Ag = X + (size_t)(bm * 128 + am) * KTOT + ah * 32;
  const int kp = lo5;
  const int ng = wv * 32 + hi1 * 16;
  const float* Bg = W + (size_t)(2 * kp) * NTOT + bn * 128 + ng;

#define LOADR(R, K0) do {                                                     \
    const float* ap_ = Ag + (K0);                                             \
    R.a0 = *(const float4*)(ap_ +  0); R.a1 = *(const float4*)(ap_ +  4);     \
    R.a2 = *(const float4*)(ap_ +  8); R.a3 = *(const float4*)(ap_ + 12);     \
    R.a4 = *(const float4*)(ap_ + 16); R.a5 = *(const float4*)(ap_ + 20);     \
    R.a6 = *(const float4*)(ap_ + 24); R.a7 = *(const float4*)(ap_ + 28);     \
    const float* bp_ = Bg + (size_t)(K0) * NTOT;                              \
    R.u0 = *(const float4*)(bp_ +  0); R.u1 = *(const float4*)(bp_ +  4);     \
    R.u2 = *(const float4*)(bp_ +  8); R.u3 = *(const float4*)(bp_ + 12);     \
    R.v0 = *(const float4*)(bp_ + NTOT +  0); R.v1 = *(const float4*)(bp_ + NTOT +  4); \
    R.v2 = *(const float4*)(bp_ + NTOT +  8); R.v3 = *(const float4*)(bp_ + NTOT + 12); \
  } while (0)

#define ASTF(R, J, P, Q)                                                      \
    *(uint4*)(Ab + abase + (((((ah << 2) + (J)) ^ amz)) << 4)) =              \
      make_uint4(pk2(R.P.x, R.P.y), pk2(R.P.z, R.P.w),                        \
                 pk2(R.Q.x, R.Q.y), pk2(R.Q.z, R.Q.w));
#define BSTF(R, I, UV, C)                                                     \
    *(uint32_t*)(Bb + (ng + (I)) * 128 + ((kp << 2) ^ (((I) & 7) << 4))) =    \
      pk2(R.u##UV.C, R.v##UV.C);

#define STORERF(R) do {                                                       \
    ASTF(R, 0, a0, a1) ASTF(R, 1, a2, a3) ASTF(R, 2, a4, a5) ASTF(R, 3, a6, a7)\
    BSTF(R, 0, 0, x) BSTF(R, 1, 0, y) BSTF(R, 2, 0, z) BSTF(R, 3, 0, w)       \
    BSTF(R, 4, 1, x) BSTF(R, 5, 1, y) BSTF(R, 6, 1, z) BSTF(R, 7, 1, w)       \
    BSTF(R, 8, 2, x) BSTF(R, 9, 2, y) BSTF(R,10, 2, z) BSTF(R,11, 2, w)       \
    BSTF(R,12, 3, x) BSTF(R,13, 3, y) BSTF(R,14, 3, z) BSTF(R,15, 3, w)       \
  } while (0)

  f32x16 acc00 = {}, acc01 = {}, acc10 = {}, acc11 = {};
  const char* Ard0 = Ab + (wr + lo5) * 128;
  const char* Ard1 = Ard0 + 32 * 128;
  const char* Brd0 = Bb + (wc + lo5) * 128;
  const char* Brd1 = Brd0 + 32 * 128;

#define MFMA_PHASE_F() do {                                                   \
    _Pragma("unroll")                                                         \
    for (int kk = 0; kk < 4; ++kk) {                                          \
      const int sb = ((((kk << 1) | hi1) ^ rs) << 4);                         \
      bf16x8 fa0 = *(const bf16x8*)(Ard0 + sb);                               \
      bf16x8 fa1 = *(const bf16x8*)(Ard1 + sb);                               \
      bf16x8 fb0 = *(const bf16x8*)(Brd0 + sb);                               \
      bf16x8 fb1 = *(const bf16x8*)(Brd1 + sb);                               \
      acc00 = __builtin_amdgcn_mfma_f32_32x32x16_bf16(fa0, fb0, acc00, 0,0,0);\
      acc01 = __builtin_amdgcn_mfma_f32_32x32x16_bf16(fa0, fb1, acc01, 0,0,0);\
      acc10 = __builtin_amdgcn_mfma_f32_32x32x16_bf16(fa1, fb0, acc10, 0,0,0);\
      acc11 = __builtin_amdgcn_mfma_f32_32x32x16_bf16(fa1, fb1, acc11, 0,0,0);\
    }                                                                         \
  } while (0)

  Regs r0, r1;
  LOADR(r0, 0);
#pragma unroll 1
  for (int s = 0; s < 8; s += 2) {
    STORERF(r0);
    __syncthreads();
    LOADR(r1, (s + 1) * 64);
    MFMA_PHASE_F();
    __syncthreads();
    STORERF(r1);
    __syncthreads();
    if (s + 2 < 8) LOADR(r0, (s + 2) * 64);
    MFMA_PHASE_F();
    __syncthreads();
  }

  const int gn0 = bn * 128 + wc + lo5;
  const int gn1 = gn0 + 32;
  const float bv0 = Bv[gn0];
  const float bv1 = Bv[gn1];
  EPI(acc00, 0, gn0, bv0);
  EPI(acc01, 0, gn1, bv1);
  EPI(acc10, 1, gn0, bv0);
  EPI(acc11, 1, gn1, bv1);
}

extern "C" void kernel_launch(void* const* d_in, const int* in_sizes, int n_in,
                              void* d_out, int out_size, void* d_ws, size_t ws_size,
                              hipStream_t stream) {
  (void)in_sizes; (void)n_in; (void)out_size;
  const float* X = (const float*)d_in[0];
  const float* W = (const float*)d_in[1];
  const float* b = (const float*)d_in[2];
  float* Y = (float*)d_out;
  if (ws_size >= WS_NEEDED) {
    uint8_t* Wt = (uint8_t*)d_ws;
    hipLaunchKernelGGL(cvtW_kernel, dim3(128),  dim3(256), 0, stream, W, Wt);
    hipLaunchKernelGGL(hotdd_fused, dim3(2048), dim3(256), 0, stream, X, Wt, b, Y);
  } else {
    hipLaunchKernelGGL(hotdd_fallback, dim3(2048), dim3(256), 0, stream, X, W, b, Y);
  }
}